// Round 1
// baseline (1751.180 us; speedup 1.0000x reference)
//
#include <hip/hip_runtime.h>
#include <hip/hip_bf16.h>

// Gather backward / scatter-add:
//   out = zeros(50000, 1024); out[indices[i], :] += grad_last[i, :]
// grad_last: [131072, 1024] f32, indices: [131072] int, out: [50000, 1024] f32.
//
// One block per grad row; 256 threads × float4 = 1024 cols. Coalesced 16B/lane
// grad reads; 4 scalar fp32 atomicAdds per thread into the target row
// (consecutive lanes -> consecutive addresses, so atomics coalesce well at L2).

#define NCOLS 1024

__global__ __launch_bounds__(256) void GatherGrad_scatter_kernel(
    const float4* __restrict__ grad, const int* __restrict__ idx,
    float* __restrict__ out, int n_idx) {
    int row = blockIdx.x;
    if (row >= n_idx) return;
    int c4 = threadIdx.x;                       // 0..255, each covers 4 cols
    int target = idx[row];

    float4 v = grad[(size_t)row * (NCOLS / 4) + c4];
    float* o = out + (size_t)target * NCOLS + (size_t)c4 * 4;
    atomicAdd(o + 0, v.x);
    atomicAdd(o + 1, v.y);
    atomicAdd(o + 2, v.z);
    atomicAdd(o + 3, v.w);
}

extern "C" void kernel_launch(void* const* d_in, const int* in_sizes, int n_in,
                              void* d_out, int out_size, void* d_ws, size_t ws_size,
                              hipStream_t stream) {
    const float4* grad = (const float4*)d_in[0];
    const int* idx = (const int*)d_in[1];
    float* out = (float*)d_out;

    int n_idx = in_sizes[1];                    // 131072

    // Zero the output (harness poisons it to 0xAA before timing).
    hipMemsetAsync(d_out, 0, (size_t)out_size * sizeof(float), stream);

    GatherGrad_scatter_kernel<<<n_idx, 256, 0, stream>>>(grad, idx, out, n_idx);
}

// Round 2
// 211.662 us; speedup vs baseline: 8.2735x; 8.2735x over previous
//
#include <hip/hip_runtime.h>
#include <hip/hip_bf16.h>

// Gather backward / scatter-add, atomics-free main pass:
//   out = zeros(50000, 1024); out[indices[i], :] += grad_last[i, :]
//
// R1 showed the scatter-atomic version is atomic/write-amplification bound
// (WRITE_SIZE = 2 GiB for a 195 MiB output, 17.6% HBM peak). This version
// builds an inverted index (CSR) in the workspace, then GATHERS:
//   1. memset counts
//   2. histogram: cnt[idx[i]]++           (int atomics, 131K)
//   3. exclusive scan of cnt -> offs      (single-block scan, 50000 elems)
//   4. fill buckets: bucket[offs[t]++]=i  (int atomics, 131K; offs becomes END)
//   5. gather: block per output row, register-accumulate its grad rows,
//      write each 4 KiB output line exactly once. Zero fp32 atomics.

#define NCOLS 1024
#define C4 (NCOLS / 4)

__global__ void hist_kernel(const int* __restrict__ idx, int* __restrict__ cnt, int n) {
    int i = blockIdx.x * blockDim.x + threadIdx.x;
    if (i < n) atomicAdd(&cnt[idx[i]], 1);
}

// Single-block exclusive scan over n ints (n up to ~64K fine).
__global__ __launch_bounds__(1024) void scan_kernel(const int* __restrict__ cnt,
                                                    int* __restrict__ offs, int n) {
    __shared__ int wave_sums[16];
    int tid = threadIdx.x;
    int lane = tid & 63, wave = tid >> 6;
    int carry = 0;
    for (int base = 0; base < n; base += 1024) {
        int i = base + tid;
        int v = (i < n) ? cnt[i] : 0;
        // wave-inclusive scan (64 lanes)
        int x = v;
        #pragma unroll
        for (int d = 1; d < 64; d <<= 1) {
            int y = __shfl_up(x, d, 64);
            if (lane >= d) x += y;
        }
        if (lane == 63) wave_sums[wave] = x;
        __syncthreads();
        if (wave == 0 && lane < 16) {
            int s = wave_sums[lane];
            #pragma unroll
            for (int d = 1; d < 16; d <<= 1) {
                int y = __shfl_up(s, d, 64);
                if (lane >= d) s += y;
            }
            wave_sums[lane] = s;   // inclusive sums across waves
        }
        __syncthreads();
        int wave_off = (wave == 0) ? 0 : wave_sums[wave - 1];
        if (i < n) offs[i] = carry + wave_off + (x - v);   // exclusive
        int total = wave_sums[15];
        __syncthreads();   // protect wave_sums before next chunk overwrites
        carry += total;
    }
}

__global__ void fill_kernel(const int* __restrict__ idx, int* __restrict__ offs,
                            int* __restrict__ bucket, int n) {
    int i = blockIdx.x * blockDim.x + threadIdx.x;
    if (i < n) {
        int slot = atomicAdd(&offs[idx[i]], 1);
        bucket[slot] = i;
    }
}

__global__ __launch_bounds__(256) void gather_kernel(
    const float4* __restrict__ grad, const int* __restrict__ cnt,
    const int* __restrict__ offs, const int* __restrict__ bucket,
    float4* __restrict__ out, int nrows) {
    int row = blockIdx.x;
    if (row >= nrows) return;
    int tid = threadIdx.x;                 // 0..255, one float4 each
    int end = offs[row];                   // offs was bumped to END by fill
    int n = cnt[row];
    float4 acc = {0.f, 0.f, 0.f, 0.f};
    for (int k = end - n; k < end; ++k) {
        int g = bucket[k];                 // wave-uniform (broadcast)
        float4 v = grad[(size_t)g * C4 + tid];
        acc.x += v.x; acc.y += v.y; acc.z += v.z; acc.w += v.w;
    }
    out[(size_t)row * C4 + tid] = acc;
}

// Fallback (R1 kernel) if workspace is too small.
__global__ __launch_bounds__(256) void scatter_atomic_kernel(
    const float4* __restrict__ grad, const int* __restrict__ idx,
    float* __restrict__ out, int n_idx) {
    int row = blockIdx.x;
    if (row >= n_idx) return;
    int c4 = threadIdx.x;
    int target = idx[row];
    float4 v = grad[(size_t)row * C4 + c4];
    float* o = out + (size_t)target * NCOLS + (size_t)c4 * 4;
    atomicAdd(o + 0, v.x);
    atomicAdd(o + 1, v.y);
    atomicAdd(o + 2, v.z);
    atomicAdd(o + 3, v.w);
}

extern "C" void kernel_launch(void* const* d_in, const int* in_sizes, int n_in,
                              void* d_out, int out_size, void* d_ws, size_t ws_size,
                              hipStream_t stream) {
    const float4* grad = (const float4*)d_in[0];
    const int* idx = (const int*)d_in[1];

    int n_idx = in_sizes[1];               // 131072
    int nrows = out_size / NCOLS;          // 50000

    size_t need = ((size_t)2 * nrows + n_idx) * sizeof(int);
    if (ws_size < need) {
        // Fallback: atomic scatter (R1 path).
        hipMemsetAsync(d_out, 0, (size_t)out_size * sizeof(float), stream);
        scatter_atomic_kernel<<<n_idx, 256, 0, stream>>>(grad, idx, (float*)d_out, n_idx);
        return;
    }

    int* cnt    = (int*)d_ws;              // [nrows]
    int* offs   = cnt + nrows;             // [nrows]
    int* bucket = offs + nrows;            // [n_idx]

    hipMemsetAsync(cnt, 0, (size_t)nrows * sizeof(int), stream);

    int blk = 256;
    hist_kernel<<<(n_idx + blk - 1) / blk, blk, 0, stream>>>(idx, cnt, n_idx);
    scan_kernel<<<1, 1024, 0, stream>>>(cnt, offs, nrows);
    fill_kernel<<<(n_idx + blk - 1) / blk, blk, 0, stream>>>(idx, offs, bucket, n_idx);
    gather_kernel<<<nrows, 256, 0, stream>>>(grad, cnt, offs, bucket,
                                             (float4*)d_out, nrows);
}

// Round 3
// 172.221 us; speedup vs baseline: 10.1682x; 1.2290x over previous
//
#include <hip/hip_runtime.h>
#include <hip/hip_bf16.h>

// Gather backward / scatter-add, atomics-free main pass, scan-free indexing:
//   out = zeros(50000, 1024); out[indices[i], :] += grad_last[i, :]
//
// R2 (CSR: hist + single-block scan + fill + gather) hit 211 µs vs ~118 µs
// traffic floor. The single-block scan serializes on one CU. This version
// uses FIXED-CAPACITY buckets (CAP=32 slots/row) so the inverted index is
// built in ONE pass with int atomics only:
//   1. memset cnt[nrows]+ovf_cnt                       (~200 KB)
//   2. fill:   local = atomicAdd(&cnt[idx[i]],1);
//              local<CAP ? bucket[idx*CAP+local]=i : overflow list
//   3. gather: block per output row, register-accumulate, one write per line
//   4. overflow: atomicAdd leftovers (empty for random data; correctness net)
//
// Max row count for 131072 uniform draws into 50000 rows is ~13 << CAP=32.

#define NCOLS 1024
#define C4 (NCOLS / 4)
#define CAP 32

__global__ void fill_kernel(const int* __restrict__ idx, int* __restrict__ cnt,
                            int* __restrict__ bucket, int* __restrict__ ovf_list,
                            int* __restrict__ ovf_cnt, int n) {
    int i = blockIdx.x * blockDim.x + threadIdx.x;
    if (i >= n) return;
    int row = idx[i];
    int local = atomicAdd(&cnt[row], 1);
    if (local < CAP) {
        bucket[(size_t)row * CAP + local] = i;
    } else {
        int s = atomicAdd(ovf_cnt, 1);
        ovf_list[s] = i;
    }
}

__global__ __launch_bounds__(256) void gather_kernel(
    const float4* __restrict__ grad, const int* __restrict__ cnt,
    const int* __restrict__ bucket, float4* __restrict__ out, int nrows) {
    int row = blockIdx.x;
    if (row >= nrows) return;
    int tid = threadIdx.x;                  // 0..255, one float4 each
    int n = cnt[row];
    if (n > CAP) n = CAP;
    const int* b = bucket + (size_t)row * CAP;
    float4 acc = {0.f, 0.f, 0.f, 0.f};
    for (int k = 0; k < n; ++k) {
        int g = b[k];                       // wave-uniform (broadcast)
        float4 v = grad[(size_t)g * C4 + tid];
        acc.x += v.x; acc.y += v.y; acc.z += v.z; acc.w += v.w;
    }
    out[(size_t)row * C4 + tid] = acc;
}

// Post-gather: add overflow entries (count > CAP) with fp32 atomics.
// Grid-stride over the overflow list; ovf_cnt==0 for this data -> ~2 us.
__global__ __launch_bounds__(256) void overflow_kernel(
    const float4* __restrict__ grad, const int* __restrict__ idx,
    const int* __restrict__ ovf_list, const int* __restrict__ ovf_cnt,
    float* __restrict__ out) {
    int n = *ovf_cnt;
    for (int e = blockIdx.x; e < n; e += gridDim.x) {
        int i = ovf_list[e];
        int row = idx[i];
        float4 v = grad[(size_t)i * C4 + threadIdx.x];
        float* o = out + (size_t)row * NCOLS + (size_t)threadIdx.x * 4;
        atomicAdd(o + 0, v.x);
        atomicAdd(o + 1, v.y);
        atomicAdd(o + 2, v.z);
        atomicAdd(o + 3, v.w);
    }
}

// Fallback (R1 kernel) if workspace is too small.
__global__ __launch_bounds__(256) void scatter_atomic_kernel(
    const float4* __restrict__ grad, const int* __restrict__ idx,
    float* __restrict__ out, int n_idx) {
    int row = blockIdx.x;
    if (row >= n_idx) return;
    int c4 = threadIdx.x;
    int target = idx[row];
    float4 v = grad[(size_t)row * C4 + c4];
    float* o = out + (size_t)target * NCOLS + (size_t)c4 * 4;
    atomicAdd(o + 0, v.x);
    atomicAdd(o + 1, v.y);
    atomicAdd(o + 2, v.z);
    atomicAdd(o + 3, v.w);
}

extern "C" void kernel_launch(void* const* d_in, const int* in_sizes, int n_in,
                              void* d_out, int out_size, void* d_ws, size_t ws_size,
                              hipStream_t stream) {
    const float4* grad = (const float4*)d_in[0];
    const int* idx = (const int*)d_in[1];

    int n_idx = in_sizes[1];               // 131072
    int nrows = out_size / NCOLS;          // 50000

    size_t need = ((size_t)nrows * (CAP + 1) + 1 + n_idx) * sizeof(int);
    if (ws_size < need) {
        // Fallback: atomic scatter (R1 path).
        hipMemsetAsync(d_out, 0, (size_t)out_size * sizeof(float), stream);
        scatter_atomic_kernel<<<n_idx, 256, 0, stream>>>(grad, idx, (float*)d_out, n_idx);
        return;
    }

    int* cnt      = (int*)d_ws;            // [nrows]
    int* ovf_cnt  = cnt + nrows;           // [1]
    int* bucket   = ovf_cnt + 1;           // [nrows * CAP]
    int* ovf_list = bucket + (size_t)nrows * CAP;  // [n_idx]

    // Zero cnt + ovf_cnt in one memset.
    hipMemsetAsync(cnt, 0, ((size_t)nrows + 1) * sizeof(int), stream);

    int blk = 256;
    fill_kernel<<<(n_idx + blk - 1) / blk, blk, 0, stream>>>(
        idx, cnt, bucket, ovf_list, ovf_cnt, n_idx);
    gather_kernel<<<nrows, 256, 0, stream>>>(grad, cnt, bucket,
                                             (float4*)d_out, nrows);
    overflow_kernel<<<128, 256, 0, stream>>>(grad, idx, ovf_list, ovf_cnt,
                                             (float*)d_out);
}

// Round 4
// 166.238 us; speedup vs baseline: 10.5342x; 1.0360x over previous
//
#include <hip/hip_runtime.h>
#include <hip/hip_bf16.h>

// Gather backward / scatter-add:
//   out = zeros(50000, 1024); out[indices[i], :] += grad_last[i, :]
//
// R3: fixed-capacity buckets -> 172 µs (floor ~119 µs). Remaining slack is
// gather-side latency: cnt load -> bucket load -> per-iter dependent grad
// loads (MLP ~1). This version packs each row's metadata into ONE 64 B line:
//   meta[row] = { cnt, slot[0..14] }   (CAP = 15)
// Gather reads the line as 4x int4 (one transaction), then issues all n grad
// float4 loads with no interleaved dependencies (load phase, then accumulate
// phase). P(count >= 15 | lambda=2.62) ~ 1e-8 per row; overflow kernel keeps
// correctness for arbitrary inputs.

#define NCOLS 1024
#define C4 (NCOLS / 4)
#define CAP 15            // slots per 64B meta line (16 ints: cnt + 15 slots)

__global__ void fill_kernel(const int* __restrict__ idx, int* __restrict__ meta,
                            int* __restrict__ ovf_list, int* __restrict__ ovf_cnt,
                            int n) {
    int i = blockIdx.x * blockDim.x + threadIdx.x;
    if (i >= n) return;
    int row = idx[i];
    int local = atomicAdd(&meta[(size_t)row * 16], 1);
    if (local < CAP) {
        meta[(size_t)row * 16 + 1 + local] = i;
    } else {
        int s = atomicAdd(ovf_cnt, 1);
        ovf_list[s] = i;
    }
}

__global__ __launch_bounds__(256) void gather_kernel(
    const float4* __restrict__ grad, const int4* __restrict__ meta4,
    float4* __restrict__ out, int nrows) {
    int row = blockIdx.x;
    if (row >= nrows) return;
    int tid = threadIdx.x;                 // 0..255, one float4 each

    // One 64B meta line: 4 parallel int4 loads.
    int4 m0 = meta4[(size_t)row * 4 + 0];
    int4 m1 = meta4[(size_t)row * 4 + 1];
    int4 m2 = meta4[(size_t)row * 4 + 2];
    int4 m3 = meta4[(size_t)row * 4 + 3];
    int n = m0.x;
    if (n > CAP) n = CAP;
    int g[CAP] = {m0.y, m0.z, m0.w,
                  m1.x, m1.y, m1.z, m1.w,
                  m2.x, m2.y, m2.z, m2.w,
                  m3.x, m3.y, m3.z, m3.w};

    // Phase 1: issue all grad loads (independent -> high MLP).
    float4 v[CAP];
    #pragma unroll
    for (int k = 0; k < CAP; ++k)
        if (k < n) v[k] = grad[(size_t)g[k] * C4 + tid];

    // Phase 2: accumulate.
    float4 acc = {0.f, 0.f, 0.f, 0.f};
    #pragma unroll
    for (int k = 0; k < CAP; ++k)
        if (k < n) {
            acc.x += v[k].x; acc.y += v[k].y;
            acc.z += v[k].z; acc.w += v[k].w;
        }

    out[(size_t)row * C4 + tid] = acc;
}

// Post-gather: add overflow entries (count > CAP) with fp32 atomics.
// Empty for this data distribution; correctness net for arbitrary inputs.
__global__ __launch_bounds__(256) void overflow_kernel(
    const float4* __restrict__ grad, const int* __restrict__ idx,
    const int* __restrict__ ovf_list, const int* __restrict__ ovf_cnt,
    float* __restrict__ out) {
    int n = *ovf_cnt;
    for (int e = blockIdx.x; e < n; e += gridDim.x) {
        int i = ovf_list[e];
        int row = idx[i];
        float4 v = grad[(size_t)i * C4 + threadIdx.x];
        float* o = out + (size_t)row * NCOLS + (size_t)threadIdx.x * 4;
        atomicAdd(o + 0, v.x);
        atomicAdd(o + 1, v.y);
        atomicAdd(o + 2, v.z);
        atomicAdd(o + 3, v.w);
    }
}

// Fallback (R1 kernel) if workspace is too small.
__global__ __launch_bounds__(256) void scatter_atomic_kernel(
    const float4* __restrict__ grad, const int* __restrict__ idx,
    float* __restrict__ out, int n_idx) {
    int row = blockIdx.x;
    if (row >= n_idx) return;
    int c4 = threadIdx.x;
    int target = idx[row];
    float4 v = grad[(size_t)row * C4 + c4];
    float* o = out + (size_t)target * NCOLS + (size_t)c4 * 4;
    atomicAdd(o + 0, v.x);
    atomicAdd(o + 1, v.y);
    atomicAdd(o + 2, v.z);
    atomicAdd(o + 3, v.w);
}

extern "C" void kernel_launch(void* const* d_in, const int* in_sizes, int n_in,
                              void* d_out, int out_size, void* d_ws, size_t ws_size,
                              hipStream_t stream) {
    const float4* grad = (const float4*)d_in[0];
    const int* idx = (const int*)d_in[1];

    int n_idx = in_sizes[1];               // 131072
    int nrows = out_size / NCOLS;          // 50000

    size_t need = ((size_t)nrows * 16 + 1 + n_idx) * sizeof(int);
    if (ws_size < need) {
        // Fallback: atomic scatter (R1 path).
        hipMemsetAsync(d_out, 0, (size_t)out_size * sizeof(float), stream);
        scatter_atomic_kernel<<<n_idx, 256, 0, stream>>>(grad, idx, (float*)d_out, n_idx);
        return;
    }

    int* meta     = (int*)d_ws;            // [nrows][16]: {cnt, slot[0..14]}
    int* ovf_cnt  = meta + (size_t)nrows * 16;      // [1]
    int* ovf_list = ovf_cnt + 1;                    // [n_idx]

    // Zero meta (cnt fields) + ovf_cnt in one contiguous memset (~3.2 MB).
    hipMemsetAsync(meta, 0, ((size_t)nrows * 16 + 1) * sizeof(int), stream);

    int blk = 256;
    fill_kernel<<<(n_idx + blk - 1) / blk, blk, 0, stream>>>(
        idx, meta, ovf_list, ovf_cnt, n_idx);
    gather_kernel<<<nrows, 256, 0, stream>>>(grad, (const int4*)meta,
                                             (float4*)d_out, nrows);
    overflow_kernel<<<128, 256, 0, stream>>>(grad, idx, ovf_list, ovf_cnt,
                                             (float*)d_out);
}

// Round 5
// 145.408 us; speedup vs baseline: 12.0433x; 1.1433x over previous
//
#include <hip/hip_runtime.h>
#include <hip/hip_bf16.h>

// Gather backward / scatter-add:
//   out = zeros(50000, 1024); out[indices[i], :] += grad_last[i, :]
//
// R4: 166 µs (floor ~120 µs @ 6.3 TB/s). Gather runs ~5.0 TB/s effective on
// random-4KB-granule reads + streaming writes. This round:
//   - overflow handling fused INTO gather (rare path: row scans ovf_list
//     itself) -> one fewer launch, zero fp32 atomics anywhere
//   - nontemporal loads (grad) / stores (out): both streams are touch-once;
//     keeps the 3.2 MB meta (fill -> gather reuse) L2-resident
//   - pipeline: memset(3.2MB) -> fill -> gather   (3 launches)

#define NCOLS 1024
#define C4 (NCOLS / 4)
#define CAP 15            // slots per 64B meta line (16 ints: cnt + 15 slots)

typedef float f4 __attribute__((ext_vector_type(4)));

__global__ void fill_kernel(const int* __restrict__ idx, int* __restrict__ meta,
                            int* __restrict__ ovf_list, int* __restrict__ ovf_cnt,
                            int n) {
    int i = blockIdx.x * blockDim.x + threadIdx.x;
    if (i >= n) return;
    int row = idx[i];
    int local = atomicAdd(&meta[(size_t)row * 16], 1);
    if (local < CAP) {
        meta[(size_t)row * 16 + 1 + local] = i;
    } else {
        int s = atomicAdd(ovf_cnt, 1);
        ovf_list[s] = i;
    }
}

__global__ __launch_bounds__(256) void gather_kernel(
    const f4* __restrict__ grad, const int4* __restrict__ meta4,
    const int* __restrict__ idx, const int* __restrict__ ovf_list,
    const int* __restrict__ ovf_cnt, f4* __restrict__ out) {
    int row = blockIdx.x;
    int tid = threadIdx.x;                 // 0..255, one float4 each

    // One 64B meta line: 4 parallel int4 loads (same addr across block ->
    // broadcast).
    int4 m0 = meta4[(size_t)row * 4 + 0];
    int4 m1 = meta4[(size_t)row * 4 + 1];
    int4 m2 = meta4[(size_t)row * 4 + 2];
    int4 m3 = meta4[(size_t)row * 4 + 3];
    int n_raw = m0.x;
    int n = n_raw > CAP ? CAP : n_raw;
    int g[CAP] = {m0.y, m0.z, m0.w,
                  m1.x, m1.y, m1.z, m1.w,
                  m2.x, m2.y, m2.z, m2.w,
                  m3.x, m3.y, m3.z, m3.w};

    // Phase 1: issue all grad loads (independent -> high MLP). Nontemporal:
    // touch-once stream, don't pollute L2.
    f4 v[CAP];
    #pragma unroll
    for (int k = 0; k < CAP; ++k)
        if (k < n) v[k] = __builtin_nontemporal_load(&grad[(size_t)g[k] * C4 + tid]);

    // Phase 2: accumulate.
    f4 acc = {0.f, 0.f, 0.f, 0.f};
    #pragma unroll
    for (int k = 0; k < CAP; ++k)
        if (k < n) acc += v[k];

    // Rare path: this row overflowed CAP. Scan the overflow list for our
    // entries (ovf is empty for the benchmark distribution; correctness net).
    if (n_raw > CAP) {
        int no = *ovf_cnt;
        for (int e = 0; e < no; ++e) {
            int i = ovf_list[e];
            if (idx[i] == row)
                acc += __builtin_nontemporal_load(&grad[(size_t)i * C4 + tid]);
        }
    }

    __builtin_nontemporal_store(acc, &out[(size_t)row * C4 + tid]);
}

// Fallback (R1 kernel) if workspace is too small.
__global__ __launch_bounds__(256) void scatter_atomic_kernel(
    const float4* __restrict__ grad, const int* __restrict__ idx,
    float* __restrict__ out, int n_idx) {
    int row = blockIdx.x;
    if (row >= n_idx) return;
    int c4 = threadIdx.x;
    int target = idx[row];
    float4 v = grad[(size_t)row * C4 + c4];
    float* o = out + (size_t)target * NCOLS + (size_t)c4 * 4;
    atomicAdd(o + 0, v.x);
    atomicAdd(o + 1, v.y);
    atomicAdd(o + 2, v.z);
    atomicAdd(o + 3, v.w);
}

extern "C" void kernel_launch(void* const* d_in, const int* in_sizes, int n_in,
                              void* d_out, int out_size, void* d_ws, size_t ws_size,
                              hipStream_t stream) {
    const float4* grad = (const float4*)d_in[0];
    const int* idx = (const int*)d_in[1];

    int n_idx = in_sizes[1];               // 131072
    int nrows = out_size / NCOLS;          // 50000

    size_t need = ((size_t)nrows * 16 + 1 + n_idx) * sizeof(int);
    if (ws_size < need) {
        // Fallback: atomic scatter (R1 path).
        hipMemsetAsync(d_out, 0, (size_t)out_size * sizeof(float), stream);
        scatter_atomic_kernel<<<n_idx, 256, 0, stream>>>(grad, idx, (float*)d_out, n_idx);
        return;
    }

    int* meta     = (int*)d_ws;            // [nrows][16]: {cnt, slot[0..14]}
    int* ovf_cnt  = meta + (size_t)nrows * 16;      // [1]
    int* ovf_list = ovf_cnt + 1;                    // [n_idx]

    // Zero meta (cnt fields) + ovf_cnt in one contiguous memset (~3.2 MB).
    hipMemsetAsync(meta, 0, ((size_t)nrows * 16 + 1) * sizeof(int), stream);

    int blk = 256;
    fill_kernel<<<(n_idx + blk - 1) / blk, blk, 0, stream>>>(
        idx, meta, ovf_list, ovf_cnt, n_idx);
    gather_kernel<<<nrows, 256, 0, stream>>>((const f4*)grad, (const int4*)meta,
                                             idx, ovf_list, ovf_cnt,
                                             (f4*)d_out);
}